// Round 3
// baseline (956.156 us; speedup 1.0000x reference)
//
// ============================================================================
// Round 16: CSR build replaced by DIRECT SCATTER (deletes count, partition,
// sort_fine -- ~150us of LDS-heavy work):
//   (1) prep: deg_in[dst]/deg_out[src] via plain global atomics (L2-resident
//       1.2MB, 9.6M atomics) | wfrag | h->bf16. (2) scan_rs: row_start =
//       exclscan(deg_in), cursor=row_start (294 blocks, redundant prefix
//       reduce, no cross-block sync). (3) pg: scatter branch
//       {pos=atomicAdd(&cursor[dst]); S[pos]=(u16)src} + gemm branch (deg_out
//       read direct -> no LDS, no syncthreads). S 9.6MB stays L2-resident so
//       2B scatter stores don't amplify to HBM.
//   spmm REVERTED to R14 exactly (node-per-group, serial-g, register acc,
//   single write): R15's LDS-atomic agg caused 513K bank conflicts + 3x out
//   RMW traffic -> 131us. Edge order within a node is now arbitrary (atomic
//   race) -- only perturbs fp32 sum order, ~1e-4 vs threshold 0.0111.
// Pipeline: memset, prep, scan_rs, pg, spmm = 5 dispatches.
//
// Measured R15: 327.9us. spmm 131.0 (conflicts 513K, WRITE 37.5MB). Non-spmm
// ~197us in BOTH R14/R15 -> CSR build work itself was the cost.
//
// Predicted: spmm back to ~69.3 (FETCH 143MB, conflicts 6.4K), pg 25-40,
// prep 15-20, scan 5-8. Total -> ~150-175us. absmax ~0.00195 +- 1e-4.
// If pg > 55: scatter atomic/store throughput model wrong.
// ============================================================================
#include <hip/hip_runtime.h>

#define KDIM 128
#define NCOLS 64
// fine buckets (spmm granularity)
#define BUCKET 64
#define NBUCK 782
#define FCAP 2816
// edge-slice blocks per graph
#define NPB 85
// prep task ranges
#define PREP_DEG (3 * NPB)     // 255 degree-count blocks
#define PREP_WF  12            // wfrag blocks
#define PREP_CONV 757          // h->bf16 blocks (grid-stride)
#define PREP_GRID (PREP_DEG + PREP_WF + PREP_CONV)  // 1024
// pg (scatter + gemm fused) ranges: scatter FIRST (long pole, memory-bound)
#define PG_SCAT (3 * NPB)            // 255
#define PG_GEMM_PER 391              // (50000+127)/128
#define PG_GEMM (3 * PG_GEMM_PER)    // 1173
#define PG_GRID (PG_SCAT + PG_GEMM)  // 1428

typedef __attribute__((ext_vector_type(8))) short bf16x8;
typedef __attribute__((ext_vector_type(4))) float f32x4;

struct GArgs {
  const int*   src[3];
  const int*   dst[3];
  const float* W[3];
  const float* b[3];
  int          E[3];
};

__device__ __forceinline__ unsigned short f2bf(float f) {
  unsigned u = __float_as_uint(f);
  u += 0x7FFFu + ((u >> 16) & 1u);   // RNE
  return (unsigned short)(u >> 16);
}
__device__ __forceinline__ float bflo(unsigned u) { return __uint_as_float(u << 16); }
__device__ __forceinline__ float bfhi(unsigned u) { return __uint_as_float(u & 0xFFFF0000u); }

// ---------------- fused front-end: deg-count | wfrag | convert --------------
__global__ __launch_bounds__(256) void prep_kernel(
    GArgs A, const float* __restrict__ h, unsigned short* __restrict__ hb,
    unsigned short* __restrict__ Wf, int* __restrict__ deg_out,
    int* __restrict__ deg_in, int N, int total8) {
  const int b = blockIdx.x;
  const int t = threadIdx.x;

  if (b < PREP_DEG) {
    // -------- per-edge degree count via global atomics (L2-resident) -------
    const int g = b / NPB;
    const int blk = b % NPB;
    const int E = A.E[g];
    const int per_block = (((E + NPB - 1) / NPB) + 3) & ~3;
    const int* __restrict__ src = A.src[g];
    const int* __restrict__ dst = A.dst[g];
    int* __restrict__ dout = deg_out + (size_t)g * N;
    int* __restrict__ din  = deg_in  + (size_t)g * N;
    const int e0 = blk * per_block;
    const int e1 = min(e0 + per_block, E);
    const int nn = max(e1 - e0, 0);
    const int nv = nn >> 2;
    const int4* s4 = (const int4*)&src[e0];
    const int4* d4 = (const int4*)&dst[e0];
    for (int v = t; v < nv; v += 256) {
      int4 s = s4[v];
      int4 d = d4[v];
      atomicAdd(&dout[s.x], 1); atomicAdd(&dout[s.y], 1);
      atomicAdd(&dout[s.z], 1); atomicAdd(&dout[s.w], 1);
      atomicAdd(&din[d.x], 1);  atomicAdd(&din[d.y], 1);
      atomicAdd(&din[d.z], 1);  atomicAdd(&din[d.w], 1);
    }
    for (int e = e0 + (nv << 2) + t; e < e1; e += 256) {
      atomicAdd(&dout[src[e]], 1);
      atomicAdd(&din[dst[e]], 1);
    }

  } else if (b < PREP_DEG + PREP_WF) {
    // -------- W -> MFMA B-fragment layout, PERMUTED columns ----------------
    // B-frag (c, lane n) holds logical W column (4n + c): MFMA C/D at lane n,
    // acc[c][r] is logical col 4n+c -> contiguous 8B epilogue store.
    int tid = (b - PREP_DEG) * 256 + t;   // < 3072 always
    int lane = tid & 63;
    int frag = (tid >> 6) & 15;
    int g = tid >> 10;
    int c = frag >> 2, kk = frag & 3;
    int n = lane & 15, quad = lane >> 4;
    const float* W = A.W[g];
    unsigned short v[8];
    #pragma unroll
    for (int j = 0; j < 8; ++j) {
      int k = 32 * kk + quad * 8 + j;
      v[j] = f2bf(W[k * 64 + 4 * n + c]);
    }
    uint4 u;
    u.x = (unsigned)v[0] | ((unsigned)v[1] << 16);
    u.y = (unsigned)v[2] | ((unsigned)v[3] << 16);
    u.z = (unsigned)v[4] | ((unsigned)v[5] << 16);
    u.w = (unsigned)v[6] | ((unsigned)v[7] << 16);
    ((uint4*)Wf)[tid] = u;

  } else {
    // -------- h fp32 -> bf16, grid-stride ----------------------------------
    const int cb = b - (PREP_DEG + PREP_WF);
    for (int i = cb * 256 + t; i < total8; i += PREP_CONV * 256) {
      const float4* hp = (const float4*)(h + (size_t)i * 8);
      float4 f0 = hp[0];
      float4 f1 = hp[1];
      uint4 u;
      u.x = (unsigned)f2bf(f0.x) | ((unsigned)f2bf(f0.y) << 16);
      u.y = (unsigned)f2bf(f0.z) | ((unsigned)f2bf(f0.w) << 16);
      u.z = (unsigned)f2bf(f1.x) | ((unsigned)f2bf(f1.y) << 16);
      u.w = (unsigned)f2bf(f1.z) | ((unsigned)f2bf(f1.w) << 16);
      ((uint4*)hb)[i] = u;
    }
  }
}

// ---------------- row_start = exclscan(deg_in); cursor = row_start ----------
// grid (98, 3), 512 thr. Each block redundantly reduces its prefix (coalesced,
// ~10MB/graph total) -- no cross-block sync needed.
__global__ __launch_bounds__(512) void scan_rs_kernel(
    const int* __restrict__ deg_in, int* __restrict__ row_start,
    int* __restrict__ cursor, int N) {
  __shared__ int sd[512];
  __shared__ int sbase;
  const int g = blockIdx.y;
  const int c = blockIdx.x;
  const int t = threadIdx.x;
  const int* __restrict__ dg = deg_in + (size_t)g * N;

  int acc = 0;
  const int c512 = c * 512;
  for (int i = t; i < c512; i += 512) acc += dg[i];
  sd[t] = acc;
  __syncthreads();
  for (int o = 256; o > 0; o >>= 1) {
    if (t < o) sd[t] += sd[t + o];
    __syncthreads();
  }
  if (t == 0) sbase = sd[0];
  __syncthreads();

  const int idx = c512 + t;
  int v = (idx < N) ? dg[idx] : 0;
  sd[t] = v;
  __syncthreads();
  for (int o = 1; o < 512; o <<= 1) {
    int add = (t >= o) ? sd[t - o] : 0;
    __syncthreads();
    sd[t] += add;
    __syncthreads();
  }
  int excl = sbase + sd[t] - v;
  if (idx < N) {
    row_start[(size_t)g * (N + 1) + idx] = excl;
    cursor[(size_t)g * N + idx] = excl;
  } else if (idx == N) {
    row_start[(size_t)g * (N + 1) + N] = excl;
  }
}

// ---------------- fused scatter + MFMA GEMM ---------------------------------
__global__ __launch_bounds__(512) void pg_kernel(
    GArgs A, const unsigned short* __restrict__ hb,
    const unsigned short* __restrict__ Wf, const int* __restrict__ deg_out,
    int* __restrict__ cursor, unsigned short* __restrict__ S,
    unsigned short* __restrict__ x, int N, int Emax) {
  const int b = blockIdx.x;
  const int t = threadIdx.x;

  if (b < PG_SCAT) {
    // ---------------- direct scatter: S[cursor[dst]++] = (u16)src ----------
    const int g = b / NPB;
    const int blk = b % NPB;
    const int E = A.E[g];
    const int per_block = (((E + NPB - 1) / NPB) + 3) & ~3;
    const int* __restrict__ src = A.src[g];
    const int* __restrict__ dst = A.dst[g];
    int* __restrict__ cur = cursor + (size_t)g * N;
    unsigned short* __restrict__ Sg = S + (size_t)g * Emax;
    const int e0 = blk * per_block;
    const int e1 = min(e0 + per_block, E);
    const int nn = max(e1 - e0, 0);
    const int nv = nn >> 2;
    const int4* s4 = (const int4*)&src[e0];
    const int4* d4 = (const int4*)&dst[e0];
    for (int v = t; v < nv; v += 512) {
      int4 s = s4[v];
      int4 d = d4[v];
      int p0 = atomicAdd(&cur[d.x], 1);
      int p1 = atomicAdd(&cur[d.y], 1);
      int p2 = atomicAdd(&cur[d.z], 1);
      int p3 = atomicAdd(&cur[d.w], 1);
      Sg[p0] = (unsigned short)s.x;
      Sg[p1] = (unsigned short)s.y;
      Sg[p2] = (unsigned short)s.z;
      Sg[p3] = (unsigned short)s.w;
    }
    for (int e = e0 + (nv << 2) + t; e < e1; e += 512) {
      int p = atomicAdd(&cur[dst[e]], 1);
      Sg[p] = (unsigned short)src[e];
    }

  } else {
    // ---------------- MFMA GEMM (no LDS, no syncthreads) -------------------
    const int gb = b - PG_SCAT;
    const int g = gb / PG_GEMM_PER;
    const int blk = gb % PG_GEMM_PER;
    const int row0 = blk * 128;
    unsigned short* __restrict__ xg = x + (size_t)g * N * NCOLS;
    const int* __restrict__ degg = deg_out + (size_t)g * N;

    const int lane = t & 63;
    const int w = t >> 6;
    const int quad = lane >> 4;
    const int n = lane & 15;

    int arow = min(row0 + w * 16 + n, N - 1);
    const unsigned short* hrow = hb + (size_t)arow * KDIM + quad * 8;
    bf16x8 a0 = *(const bf16x8*)(hrow);
    bf16x8 a1 = *(const bf16x8*)(hrow + 32);
    bf16x8 a2 = *(const bf16x8*)(hrow + 64);
    bf16x8 a3 = *(const bf16x8*)(hrow + 96);

    const uint4* wfp = (const uint4*)Wf + (size_t)g * 1024 + lane;

    f32x4 acc[4];
    #pragma unroll
    for (int c = 0; c < 4; ++c) acc[c] = (f32x4)(0.f);

    #pragma unroll
    for (int c = 0; c < 4; ++c) {
      union { uint4 u; bf16x8 v; } b0, b1, b2, b3;
      b0.u = wfp[(size_t)(c * 4 + 0) * 64];
      b1.u = wfp[(size_t)(c * 4 + 1) * 64];
      b2.u = wfp[(size_t)(c * 4 + 2) * 64];
      b3.u = wfp[(size_t)(c * 4 + 3) * 64];
      acc[c] = __builtin_amdgcn_mfma_f32_16x16x32_bf16(a0, b0.v, acc[c], 0, 0, 0);
      acc[c] = __builtin_amdgcn_mfma_f32_16x16x32_bf16(a1, b1.v, acc[c], 0, 0, 0);
      acc[c] = __builtin_amdgcn_mfma_f32_16x16x32_bf16(a2, b2.v, acc[c], 0, 0, 0);
      acc[c] = __builtin_amdgcn_mfma_f32_16x16x32_bf16(a3, b3.v, acc[c], 0, 0, 0);
    }

    const int rbase = row0 + w * 16 + quad * 4;
    #pragma unroll
    for (int r = 0; r < 4; ++r) {
      int row = rbase + r;
      if (row < N) {
        float dg = (float)degg[row];
        float s = rsqrtf(fmaxf(dg, 1.0f));
        uint2 o;
        o.x = (unsigned)f2bf(acc[0][r] * s) | ((unsigned)f2bf(acc[1][r] * s) << 16);
        o.y = (unsigned)f2bf(acc[2][r] * s) | ((unsigned)f2bf(acc[3][r] * s) << 16);
        *(uint2*)(xg + (size_t)row * NCOLS + 4 * n) = o;
      }
    }
  }
}

// ---------------- bucket SpMM (R14-exact) -----------------------------------
__global__ __launch_bounds__(512) void spmm_all_kernel(
    GArgs A, const unsigned short* __restrict__ S,
    const int* __restrict__ row_start, const unsigned short* __restrict__ x,
    float* __restrict__ out, int N, int Emax) {
  __shared__ int rs[BUCKET + 1];
  __shared__ unsigned short srcs[FCAP];

  const int t = threadIdx.x;
  const int bk = blockIdx.x;
  const int dbase = bk * BUCKET;
  const int nd = min(BUCKET, N - dbase);
  const int grp = t >> 3;
  const int qe = (t & 7) * 8;

  float tot[8];
  #pragma unroll
  for (int j = 0; j < 8; ++j) tot[j] = 0.f;

  for (int g = 0; g < 3; ++g) {
    const unsigned short* __restrict__ Sg = S + (size_t)g * Emax;
    const int* __restrict__ rsg = row_start + (size_t)g * (N + 1);
    const unsigned short* __restrict__ xg = x + (size_t)g * N * NCOLS;

    __syncthreads();
    if (t <= BUCKET) rs[t] = rsg[min(dbase + t, N)];
    __syncthreads();
    const int e0 = rs[0];
    const int ne = min(rs[BUCKET] - e0, FCAP);
    for (int i = t; i < ne; i += 512) srcs[i] = Sg[e0 + i];
    __syncthreads();

    if (grp < nd) {
      int i = rs[grp] - e0;
      const int iend = min(rs[grp + 1] - e0, ne);
      const int deg = iend - i;
      float acc[8];
      #pragma unroll
      for (int j = 0; j < 8; ++j) acc[j] = 0.f;
      for (; i + 3 < iend; i += 4) {
        int sa = srcs[i + 0];
        int sb = srcs[i + 1];
        int sc = srcs[i + 2];
        int sdd = srcs[i + 3];
        uint4 ua = *(const uint4*)&xg[(size_t)sa * NCOLS + qe];
        uint4 ub = *(const uint4*)&xg[(size_t)sb * NCOLS + qe];
        uint4 uc = *(const uint4*)&xg[(size_t)sc * NCOLS + qe];
        uint4 ud = *(const uint4*)&xg[(size_t)sdd * NCOLS + qe];
        acc[0] += bflo(ua.x) + bflo(ub.x) + bflo(uc.x) + bflo(ud.x);
        acc[1] += bfhi(ua.x) + bfhi(ub.x) + bfhi(uc.x) + bfhi(ud.x);
        acc[2] += bflo(ua.y) + bflo(ub.y) + bflo(uc.y) + bflo(ud.y);
        acc[3] += bfhi(ua.y) + bfhi(ub.y) + bfhi(uc.y) + bfhi(ud.y);
        acc[4] += bflo(ua.z) + bflo(ub.z) + bflo(uc.z) + bflo(ud.z);
        acc[5] += bfhi(ua.z) + bfhi(ub.z) + bfhi(uc.z) + bfhi(ud.z);
        acc[6] += bflo(ua.w) + bflo(ub.w) + bflo(uc.w) + bflo(ud.w);
        acc[7] += bfhi(ua.w) + bfhi(ub.w) + bfhi(uc.w) + bfhi(ud.w);
      }
      for (; i < iend; ++i) {
        int s = srcs[i];
        uint4 u = *(const uint4*)&xg[(size_t)s * NCOLS + qe];
        acc[0] += bflo(u.x); acc[1] += bfhi(u.x);
        acc[2] += bflo(u.y); acc[3] += bfhi(u.y);
        acc[4] += bflo(u.z); acc[5] += bfhi(u.z);
        acc[6] += bflo(u.w); acc[7] += bfhi(u.w);
      }
      float sc2 = rsqrtf(fmaxf((float)deg, 1.0f));
      const float* bg = A.b[g] + qe;
      #pragma unroll
      for (int j = 0; j < 8; ++j)
        tot[j] += fmaxf(fmaf(acc[j], sc2, bg[j]), 0.f) * (1.0f / 3.0f);
    }
  }

  if (grp < nd) {
    float* op = &out[(size_t)(dbase + grp) * NCOLS + qe];
    *(float4*)&op[0] = make_float4(tot[0], tot[1], tot[2], tot[3]);
    *(float4*)&op[4] = make_float4(tot[4], tot[5], tot[6], tot[7]);
  }
}

extern "C" void kernel_launch(void* const* d_in, const int* in_sizes, int n_in,
                              void* d_out, int out_size, void* d_ws, size_t ws_size,
                              hipStream_t stream) {
  const float* h = (const float*)d_in[0];
  const int N = in_sizes[0] / KDIM;   // 50000
  float* out = (float*)d_out;

  GArgs A;
  int Emax = 0;
  for (int g = 0; g < 3; ++g) {
    A.src[g] = (const int*)  d_in[1 + g * 4];
    A.dst[g] = (const int*)  d_in[2 + g * 4];
    A.W[g]   = (const float*)d_in[3 + g * 4];
    A.b[g]   = (const float*)d_in[4 + g * 4];
    A.E[g]   = in_sizes[1 + g * 4];
    if (A.E[g] > Emax) Emax = A.E[g];
  }

  // ws: x 19.2 | hb 12.8 | S 9.6 | Wf 48K | deg_out/deg_in/cursor/rs ~2.4 MB
  char* w = (char*)d_ws;
  unsigned short* x = (unsigned short*)w;
  char* w2 = w + (size_t)3 * N * NCOLS * sizeof(unsigned short);
  unsigned short* hb = (unsigned short*)w2;
  char* w3 = w2 + (size_t)N * KDIM * sizeof(unsigned short);
  unsigned short* S = (unsigned short*)w3;
  char* w4 = w3 + (size_t)3 * Emax * sizeof(unsigned short);
  unsigned short* Wf = (unsigned short*)w4;            // 3*16*64*8 u16 = 48 KB
  char* w5 = w4 + (size_t)3 * 16 * 64 * 8 * sizeof(unsigned short);
  int* deg_out = (int*)w5;                             // [3][N]
  int* deg_in  = deg_out + (size_t)3 * N;              // [3][N] (zeroed with deg_out)
  int* cursor  = deg_in + (size_t)3 * N;               // [3][N]
  int* row_start = cursor + (size_t)3 * N;             // [3][N+1]

  hipMemsetAsync(deg_out, 0, (size_t)2 * 3 * N * sizeof(int), stream);
  const int total8 = N * KDIM / 8;
  prep_kernel<<<PREP_GRID, 256, 0, stream>>>(A, h, hb, Wf, deg_out, deg_in, N, total8);
  scan_rs_kernel<<<dim3(98, 3), 512, 0, stream>>>(deg_in, row_start, cursor, N);
  pg_kernel<<<PG_GRID, 512, 0, stream>>>(A, hb, Wf, deg_out, cursor, S, x, N, Emax);
  spmm_all_kernel<<<NBUCK, 512, 0, stream>>>(A, S, row_start, x, out, N, Emax);
}

// Round 4
// 480.750 us; speedup vs baseline: 1.9889x; 1.9889x over previous
//
// ============================================================================
// Round 17: FULL REVERT to R14 pipeline (268.7us measured; R15 LDS-atomic agg
// and R16 direct-scatter both catastrophically regressed) + ONE isolated
// change: spmm serial-g loop split across blocks (grid 782x3). Node-per-group
// REGISTER accumulation kept (no LDS atomics, no edge balancing); epilogue is
// bias+relu+/3 then fp32 atomicAdd into out (out zeroed in prep conv branch,
// R15-verified). Removes inter-g barriers, 3x block supply (9.2 blocks/CU vs
// 4-resident cap -> ramp/tail shrinks), block lifetime /3.
//
// Measured R16: 956us. pg 415 (WRITE 322MB vs 9.7MB useful: random 2B scatter
// = line-granularity write amplification across 8 non-coherent L2s); ~460us
// unaccounted = dense global-atomic degree hist. Lesson: coarse-partition +
// LDS-sort IS the cache-correct scatter; keep it.
//
// Predicted: spmm 69.3 -> 48-58 (Occ >=55%, WRITE 37.5MB, FETCH ~155MB,
// conflicts ~6.4K); all else returns to R14 values; total -> ~248-258.
// absmax ~0.00195 (+-1ulp atomic ordering). Pre-commit: spmm >= 65 =>
// gather is L3-latency-bound -> next: column-split L2-resident x passes.
// ============================================================================
#include <hip/hip_runtime.h>

#define KDIM 128
#define NCOLS 64
// u8-packed src-degree histogram: one range, 50000 bins / 4 per word
#define NHCH 64
#define HW 12500
// coarse buckets
#define COARSE 512
#define NC 98
#define SFCAP 17408
// fine buckets (spmm granularity)
#define BUCKET 64
#define NBUCK 782
#define FCAP 2816
// partition blocks per graph
#define NPB 85
// prep task ranges
#define PREP_HIST (3 * NHCH)   // 192 hist blocks
#define PREP_CNT  (3 * NPB)    // 255 coarse-count blocks
#define PREP_WF   12           // wfrag blocks
#define PREP_CONV 565          // convert + out-zero blocks (grid-stride)
#define PREP_GRID (PREP_HIST + PREP_CNT + PREP_WF + PREP_CONV)  // 1024

typedef __attribute__((ext_vector_type(8))) short bf16x8;
typedef __attribute__((ext_vector_type(4))) float f32x4;

struct GArgs {
  const int*   src[3];
  const int*   dst[3];
  const float* W[3];
  const float* b[3];
  int          E[3];
};

__device__ __forceinline__ unsigned short f2bf(float f) {
  unsigned u = __float_as_uint(f);
  u += 0x7FFFu + ((u >> 16) & 1u);   // RNE
  return (unsigned short)(u >> 16);
}
__device__ __forceinline__ float bflo(unsigned u) { return __uint_as_float(u << 16); }
__device__ __forceinline__ float bfhi(unsigned u) { return __uint_as_float(u & 0xFFFF0000u); }

// ---------------- fused front-end: hist | count | wfrag | convert+zero ------
__global__ __launch_bounds__(256) void prep_kernel(
    GArgs A, const float* __restrict__ h, unsigned short* __restrict__ hb,
    unsigned short* __restrict__ Wf, unsigned* __restrict__ P8,
    int* __restrict__ tot, float* __restrict__ outz, int total8) {
  __shared__ unsigned sbuf[HW];   // 50 KB; hist uses all, count reuses prefix
  const int b = blockIdx.x;
  const int t = threadIdx.x;

  if (b < PREP_HIST) {
    // -------- u8-packed src histogram, single pass over all 50000 bins -----
    const int g = b >> 6;
    const int chunk = b & 63;
    const int E = A.E[g];
    const int per_chunk = (((E + NHCH - 1) / NHCH) + 3) & ~3;
    const int* __restrict__ keys = A.src[g];
    for (int i = t; i < HW; i += 256) sbuf[i] = 0;
    __syncthreads();
    const int e0 = chunk * per_chunk;
    const int e1 = min(e0 + per_chunk, E);
    const int nn = max(e1 - e0, 0);
    const int nv = nn >> 2;
    const int4* k4p = (const int4*)&keys[e0];
    for (int v = t; v < nv; v += 256) {
      int4 k = k4p[v];
      atomicAdd(&sbuf[(unsigned)k.x >> 2], 1u << (((unsigned)k.x & 3u) * 8));
      atomicAdd(&sbuf[(unsigned)k.y >> 2], 1u << (((unsigned)k.y & 3u) * 8));
      atomicAdd(&sbuf[(unsigned)k.z >> 2], 1u << (((unsigned)k.z & 3u) * 8));
      atomicAdd(&sbuf[(unsigned)k.w >> 2], 1u << (((unsigned)k.w & 3u) * 8));
    }
    for (int e = e0 + (nv << 2) + t; e < e1; e += 256) {
      unsigned k = (unsigned)keys[e];
      atomicAdd(&sbuf[k >> 2], 1u << ((k & 3u) * 8));
    }
    __syncthreads();
    unsigned* __restrict__ dstp = P8 + (size_t)b * HW;   // b == g*64+chunk
    for (int i = t; i < HW; i += 256) dstp[i] = sbuf[i];

  } else if (b < PREP_HIST + PREP_CNT) {
    // -------- coarse dst-bin count -----------------------------------------
    const int bb = b - PREP_HIST;
    const int g = bb / NPB;
    const int blk = bb % NPB;
    const int E = A.E[g];
    const int per_block = (((E + NPB - 1) / NPB) + 3) & ~3;
    const int* __restrict__ dst = A.dst[g];
    int* hcnt = (int*)sbuf;
    if (t < NC) hcnt[t] = 0;
    __syncthreads();
    const int e0 = blk * per_block;
    const int e1 = min(e0 + per_block, E);
    const int nn = max(e1 - e0, 0);
    const int nv = nn >> 2;
    const int4* d4 = (const int4*)&dst[e0];
    for (int v = t; v < nv; v += 256) {
      int4 d = d4[v];
      atomicAdd(&hcnt[(unsigned)d.x >> 9], 1);
      atomicAdd(&hcnt[(unsigned)d.y >> 9], 1);
      atomicAdd(&hcnt[(unsigned)d.z >> 9], 1);
      atomicAdd(&hcnt[(unsigned)d.w >> 9], 1);
    }
    for (int e = e0 + (nv << 2) + t; e < e1; e += 256)
      atomicAdd(&hcnt[(unsigned)dst[e] >> 9], 1);
    __syncthreads();
    if (t < NC && hcnt[t]) atomicAdd(&tot[g * NC + t], hcnt[t]);

  } else if (b < PREP_HIST + PREP_CNT + PREP_WF) {
    // -------- W -> MFMA B-fragment layout, PERMUTED columns ----------------
    // B-frag (c, lane n) holds logical W column (4n + c): MFMA C/D at lane n,
    // acc[c][r] is logical col 4n+c -> contiguous 8B epilogue store.
    int tid = (b - PREP_HIST - PREP_CNT) * 256 + t;   // < 3072 always
    int lane = tid & 63;
    int frag = (tid >> 6) & 15;
    int g = tid >> 10;
    int c = frag >> 2, kk = frag & 3;
    int n = lane & 15, quad = lane >> 4;
    const float* W = A.W[g];
    unsigned short v[8];
    #pragma unroll
    for (int j = 0; j < 8; ++j) {
      int k = 32 * kk + quad * 8 + j;
      v[j] = f2bf(W[k * 64 + 4 * n + c]);
    }
    uint4 u;
    u.x = (unsigned)v[0] | ((unsigned)v[1] << 16);
    u.y = (unsigned)v[2] | ((unsigned)v[3] << 16);
    u.z = (unsigned)v[4] | ((unsigned)v[5] << 16);
    u.w = (unsigned)v[6] | ((unsigned)v[7] << 16);
    ((uint4*)Wf)[tid] = u;

  } else {
    // -------- h fp32 -> bf16, and zero out (spmm accumulates atomically) ---
    const int cb = b - (PREP_HIST + PREP_CNT + PREP_WF);
    for (int i = cb * 256 + t; i < total8; i += PREP_CONV * 256) {
      const float4* hp = (const float4*)(h + (size_t)i * 8);
      float4 f0 = hp[0];
      float4 f1 = hp[1];
      uint4 u;
      u.x = (unsigned)f2bf(f0.x) | ((unsigned)f2bf(f0.y) << 16);
      u.y = (unsigned)f2bf(f0.z) | ((unsigned)f2bf(f0.w) << 16);
      u.z = (unsigned)f2bf(f1.x) | ((unsigned)f2bf(f1.y) << 16);
      u.w = (unsigned)f2bf(f1.z) | ((unsigned)f2bf(f1.w) << 16);
      ((uint4*)hb)[i] = u;
    }
    const int nout4 = total8;   // N*64 floats / 4 == N*128/8
    const float4 z = make_float4(0.f, 0.f, 0.f, 0.f);
    for (int i = cb * 256 + t; i < nout4; i += PREP_CONV * 256)
      ((float4*)outz)[i] = z;
  }
}

// ---------------- exact scan ------------------------------------------------
__global__ __launch_bounds__(128) void scan_off_kernel(
    const int* __restrict__ tot, int* __restrict__ off, int* __restrict__ cursor) {
  __shared__ int sd[128];
  const int t = threadIdx.x;
  for (int g = 0; g < 3; ++g) {
    int v = (t < NC) ? tot[g * NC + t] : 0;
    sd[t] = v;
    __syncthreads();
    for (int o = 1; o < 128; o <<= 1) {
      int add = (t >= o) ? sd[t - o] : 0;
      __syncthreads();
      sd[t] += add;
      __syncthreads();
    }
    int excl = sd[t] - v;
    if (t < NC) { off[g * (NC + 1) + t] = excl; cursor[g * NC + t] = excl; }
    if (t == 0) off[g * (NC + 1) + NC] = sd[127];
    __syncthreads();
  }
}

// ---------------- coarse partition ------------------------------------------
__global__ __launch_bounds__(256) void partition_coarse_kernel(
    GArgs A, int* __restrict__ cursor, unsigned* __restrict__ P2c, int Emax) {
  __shared__ int lcnt[NC];
  __shared__ int lcur[NC];
  const int g = blockIdx.y;
  const int E = A.E[g];
  const int per_block = (((E + NPB - 1) / NPB) + 3) & ~3;
  const int* __restrict__ src = A.src[g];
  const int* __restrict__ dst = A.dst[g];
  unsigned* __restrict__ P2g = P2c + (size_t)g * Emax;
  const int t = threadIdx.x;
  if (t < NC) lcnt[t] = 0;
  __syncthreads();
  const int e0 = blockIdx.x * per_block;
  const int e1 = min(e0 + per_block, E);
  const int n = max(e1 - e0, 0);
  const int nv = n >> 2;
  const int4* d4 = (const int4*)&dst[e0];
  const int4* s4 = (const int4*)&src[e0];
  for (int v = t; v < nv; v += 256) {
    int4 d = d4[v];
    atomicAdd(&lcnt[(unsigned)d.x >> 9], 1);
    atomicAdd(&lcnt[(unsigned)d.y >> 9], 1);
    atomicAdd(&lcnt[(unsigned)d.z >> 9], 1);
    atomicAdd(&lcnt[(unsigned)d.w >> 9], 1);
  }
  for (int e = e0 + (nv << 2) + t; e < e1; e += 256)
    atomicAdd(&lcnt[(unsigned)dst[e] >> 9], 1);
  __syncthreads();
  if (t < NC) {
    int c = lcnt[t];
    lcur[t] = c ? atomicAdd(&cursor[g * NC + t], c) : 0;
  }
  __syncthreads();
  for (int v = t; v < nv; v += 256) {
    int4 d = d4[v];
    int4 s = s4[v];
    unsigned bk; int pos;
    bk = (unsigned)d.x >> 9; pos = atomicAdd(&lcur[bk], 1);
    P2g[pos] = (unsigned)s.x | (((unsigned)d.x & 511u) << 16);
    bk = (unsigned)d.y >> 9; pos = atomicAdd(&lcur[bk], 1);
    P2g[pos] = (unsigned)s.y | (((unsigned)d.y & 511u) << 16);
    bk = (unsigned)d.z >> 9; pos = atomicAdd(&lcur[bk], 1);
    P2g[pos] = (unsigned)s.z | (((unsigned)d.z & 511u) << 16);
    bk = (unsigned)d.w >> 9; pos = atomicAdd(&lcur[bk], 1);
    P2g[pos] = (unsigned)s.w | (((unsigned)d.w & 511u) << 16);
  }
  for (int e = e0 + (nv << 2) + t; e < e1; e += 256) {
    unsigned d = (unsigned)dst[e];
    unsigned bk = d >> 9;
    int pos = atomicAdd(&lcur[bk], 1);
    P2g[pos] = (unsigned)src[e] | ((d & 511u) << 16);
  }
}

// ---------------- fine sort -------------------------------------------------
__global__ __launch_bounds__(512) void sort_fine_kernel(
    const unsigned* __restrict__ P2c, const int* __restrict__ off,
    unsigned short* __restrict__ S, int* __restrict__ row_start,
    int N, int Emax) {
  __shared__ int cnt[COARSE];
  __shared__ int sd[COARSE];
  __shared__ int cur[COARSE];
  __shared__ unsigned short outl[SFCAP];
  const int c = blockIdx.x;
  const int g = blockIdx.y;
  const unsigned* __restrict__ P2g = P2c + (size_t)g * Emax;
  const int base_e = off[g * (NC + 1) + c];
  const int nloc = off[g * (NC + 1) + c + 1] - base_e;
  const int t = threadIdx.x;

  cnt[t] = 0;
  __syncthreads();
  for (int i = t; i < nloc; i += 512)
    atomicAdd(&cnt[(P2g[base_e + i] >> 16) & 511u], 1);
  __syncthreads();
  int v = cnt[t];
  sd[t] = v;
  __syncthreads();
  for (int o = 1; o < 512; o <<= 1) {
    int add = (t >= o) ? sd[t - o] : 0;
    __syncthreads();
    sd[t] += add;
    __syncthreads();
  }
  int excl = sd[t] - v;
  cur[t] = excl;
  int node = c * COARSE + t;
  if (node <= N) row_start[g * (N + 1) + node] = base_e + excl;
  __syncthreads();
  for (int i = t; i < nloc; i += 512) {
    unsigned p = P2g[base_e + i];
    int pos = atomicAdd(&cur[(p >> 16) & 511u], 1);
    if (pos < SFCAP) outl[pos] = (unsigned short)(p & 0xFFFFu);
  }
  __syncthreads();
  unsigned short* __restrict__ Sg = S + (size_t)g * Emax;
  for (int i = t; i < nloc; i += 512) Sg[base_e + i] = outl[i];
}

// ---------------- MFMA GEMM: x(bf16) = (hb @ W) * rsqrt(deg_out) ------------
__global__ __launch_bounds__(512) void gemm_mfma_kernel(
    GArgs A, const unsigned short* __restrict__ hb,
    const unsigned short* __restrict__ Wf, const unsigned* __restrict__ P8,
    unsigned short* __restrict__ x, int N) {
  __shared__ unsigned ldegw[64];   // [word 0..31][half 0..1] u16-packed degrees
  const int g = blockIdx.y;
  unsigned short* __restrict__ xg = x + (size_t)g * N * NCOLS;
  const int t = threadIdx.x;
  const int row0 = blockIdx.x * 128;

  if (t < 64) ldegw[t] = 0;
  __syncthreads();
  if (t < 256) {
    // 32 words x 8 chunk-groups; SWAR-sum 8 chunks then 2 LDS atomics
    const unsigned* __restrict__ Pg = P8 + (size_t)g * NHCH * HW;
    const int widx = t >> 3;
    const int cg = t & 7;
    const int wcol = min((row0 >> 2) + widx, HW - 1);
    unsigned lo = 0, hi = 0;
    #pragma unroll
    for (int cc = 0; cc < 8; ++cc) {
      unsigned wv = Pg[(size_t)(cg * 8 + cc) * HW + wcol];
      lo += wv & 0x00FF00FFu;
      hi += (wv >> 8) & 0x00FF00FFu;
    }
    atomicAdd(&ldegw[2 * widx], lo);
    atomicAdd(&ldegw[2 * widx + 1], hi);
  }

  const int lane = t & 63;
  const int w = t >> 6;              // wave id: rows row0+16w .. +15
  const int quad = lane >> 4;
  const int n = lane & 15;

  // A fragments: lane holds row (row0+16w+n), k = quad*8+j (+32 per frag)
  int arow = min(row0 + w * 16 + n, N - 1);
  const unsigned short* hrow = hb + (size_t)arow * KDIM + quad * 8;
  bf16x8 a0 = *(const bf16x8*)(hrow);
  bf16x8 a1 = *(const bf16x8*)(hrow + 32);
  bf16x8 a2 = *(const bf16x8*)(hrow + 64);
  bf16x8 a3 = *(const bf16x8*)(hrow + 96);

  const uint4* wfp = (const uint4*)Wf + (size_t)g * 1024 + lane;

  f32x4 acc[4];
  #pragma unroll
  for (int c = 0; c < 4; ++c) acc[c] = (f32x4)(0.f);

  __syncthreads();   // ldegw ready

  #pragma unroll
  for (int c = 0; c < 4; ++c) {
    union { uint4 u; bf16x8 v; } b0, b1, b2, b3;
    b0.u = wfp[(size_t)(c * 4 + 0) * 64];
    b1.u = wfp[(size_t)(c * 4 + 1) * 64];
    b2.u = wfp[(size_t)(c * 4 + 2) * 64];
    b3.u = wfp[(size_t)(c * 4 + 3) * 64];
    acc[c] = __builtin_amdgcn_mfma_f32_16x16x32_bf16(a0, b0.v, acc[c], 0, 0, 0);
    acc[c] = __builtin_amdgcn_mfma_f32_16x16x32_bf16(a1, b1.v, acc[c], 0, 0, 0);
    acc[c] = __builtin_amdgcn_mfma_f32_16x16x32_bf16(a2, b2.v, acc[c], 0, 0, 0);
    acc[c] = __builtin_amdgcn_mfma_f32_16x16x32_bf16(a3, b3.v, acc[c], 0, 0, 0);
  }

  // epilogue: C/D row = quad*4 + r, lane n owns logical cols 4n..4n+3
  const int rbase = row0 + w * 16 + quad * 4;
  #pragma unroll
  for (int r = 0; r < 4; ++r) {
    int row = rbase + r;
    if (row < N) {
      int lr = row - row0;
      float dg = (float)((ldegw[2 * (lr >> 2) + (lr & 1)] >> (((lr >> 1) & 1) * 16)) & 0xFFFFu);
      float s = rsqrtf(fmaxf(dg, 1.0f));
      uint2 o;
      o.x = (unsigned)f2bf(acc[0][r] * s) | ((unsigned)f2bf(acc[1][r] * s) << 16);
      o.y = (unsigned)f2bf(acc[2][r] * s) | ((unsigned)f2bf(acc[3][r] * s) << 16);
      *(uint2*)(xg + (size_t)row * NCOLS + 4 * n) = o;
    }
  }
}

// ---------------- bucket SpMM: per-(bucket,g), register acc, atomic out -----
__global__ __launch_bounds__(512) void spmm_all_kernel(
    GArgs A, const unsigned short* __restrict__ S,
    const int* __restrict__ row_start, const unsigned short* __restrict__ x,
    float* __restrict__ out, int N, int Emax) {
  __shared__ int rs[BUCKET + 1];
  __shared__ unsigned short srcs[FCAP];

  const int t = threadIdx.x;
  const int g = blockIdx.y;
  const int bk = blockIdx.x;
  const int dbase = bk * BUCKET;
  const int nd = min(BUCKET, N - dbase);
  const int grp = t >> 3;
  const int qe = (t & 7) * 8;

  const unsigned short* __restrict__ Sg = S + (size_t)g * Emax;
  const int* __restrict__ rsg = row_start + (size_t)g * (N + 1);
  const unsigned short* __restrict__ xg = x + (size_t)g * N * NCOLS;

  if (t <= BUCKET) rs[t] = rsg[min(dbase + t, N)];
  __syncthreads();
  const int e0 = rs[0];
  const int ne = min(rs[BUCKET] - e0, FCAP);
  for (int i = t; i < ne; i += 512) srcs[i] = Sg[e0 + i];
  __syncthreads();

  if (grp < nd) {
    int i = rs[grp] - e0;
    const int iend = min(rs[grp + 1] - e0, ne);
    const int deg = iend - i;
    float acc[8];
    #pragma unroll
    for (int j = 0; j < 8; ++j) acc[j] = 0.f;
    for (; i + 3 < iend; i += 4) {
      int sa = srcs[i + 0];
      int sb = srcs[i + 1];
      int sc = srcs[i + 2];
      int sdd = srcs[i + 3];
      uint4 ua = *(const uint4*)&xg[(size_t)sa * NCOLS + qe];
      uint4 ub = *(const uint4*)&xg[(size_t)sb * NCOLS + qe];
      uint4 uc = *(const uint4*)&xg[(size_t)sc * NCOLS + qe];
      uint4 ud = *(const uint4*)&xg[(size_t)sdd * NCOLS + qe];
      acc[0] += bflo(ua.x) + bflo(ub.x) + bflo(uc.x) + bflo(ud.x);
      acc[1] += bfhi(ua.x) + bfhi(ub.x) + bfhi(uc.x) + bfhi(ud.x);
      acc[2] += bflo(ua.y) + bflo(ub.y) + bflo(uc.y) + bflo(ud.y);
      acc[3] += bfhi(ua.y) + bfhi(ub.y) + bfhi(uc.y) + bfhi(ud.y);
      acc[4] += bflo(ua.z) + bflo(ub.z) + bflo(uc.z) + bflo(ud.z);
      acc[5] += bfhi(ua.z) + bfhi(ub.z) + bfhi(uc.z) + bfhi(ud.z);
      acc[6] += bflo(ua.w) + bflo(ub.w) + bflo(uc.w) + bflo(ud.w);
      acc[7] += bfhi(ua.w) + bfhi(ub.w) + bfhi(uc.w) + bfhi(ud.w);
    }
    for (; i < iend; ++i) {
      int s = srcs[i];
      uint4 u = *(const uint4*)&xg[(size_t)s * NCOLS + qe];
      acc[0] += bflo(u.x); acc[1] += bfhi(u.x);
      acc[2] += bflo(u.y); acc[3] += bfhi(u.y);
      acc[4] += bflo(u.z); acc[5] += bfhi(u.z);
      acc[6] += bflo(u.w); acc[7] += bfhi(u.w);
    }
    float sc2 = rsqrtf(fmaxf((float)deg, 1.0f));
    const float* bg = A.b[g] + qe;
    float* op = &out[(size_t)(dbase + grp) * NCOLS + qe];
    #pragma unroll
    for (int j = 0; j < 8; ++j)
      atomicAdd(&op[j], fmaxf(fmaf(acc[j], sc2, bg[j]), 0.f) * (1.0f / 3.0f));
  }
}

extern "C" void kernel_launch(void* const* d_in, const int* in_sizes, int n_in,
                              void* d_out, int out_size, void* d_ws, size_t ws_size,
                              hipStream_t stream) {
  const float* h = (const float*)d_in[0];
  const int N = in_sizes[0] / KDIM;   // 50000
  float* out = (float*)d_out;

  GArgs A;
  int Emax = 0;
  for (int g = 0; g < 3; ++g) {
    A.src[g] = (const int*)  d_in[1 + g * 4];
    A.dst[g] = (const int*)  d_in[2 + g * 4];
    A.W[g]   = (const float*)d_in[3 + g * 4];
    A.b[g]   = (const float*)d_in[4 + g * 4];
    A.E[g]   = in_sizes[1 + g * 4];
    if (A.E[g] > Emax) Emax = A.E[g];
  }

  // ws: x 19.2 | hb 12.8 | P2c 19.2 | P8 9.6 | S 9.6 | Wf 48K | rs 0.6 MB
  char* w = (char*)d_ws;
  unsigned short* x = (unsigned short*)w;
  char* w2 = w + (size_t)3 * N * NCOLS * sizeof(unsigned short);
  unsigned short* hb = (unsigned short*)w2;
  char* w3 = w2 + (size_t)N * KDIM * sizeof(unsigned short);
  unsigned* P2c = (unsigned*)w3;
  char* w4 = w3 + (size_t)3 * Emax * sizeof(unsigned);
  unsigned* P8 = (unsigned*)w4;
  char* w5 = w4 + (size_t)3 * NHCH * HW * sizeof(unsigned);
  unsigned short* S = (unsigned short*)w5;
  char* w6 = w5 + (size_t)3 * Emax * sizeof(unsigned short);
  unsigned short* Wf = (unsigned short*)w6;            // 3*16*64*8 u16 = 48 KB
  char* w7 = w6 + (size_t)3 * 16 * 64 * 8 * sizeof(unsigned short);
  int* row_start = (int*)w7;
  char* w8 = w7 + (size_t)3 * (N + 1) * sizeof(int);
  int* tot    = (int*)w8;
  int* off    = tot + 3 * NC;
  int* cursor = off + 3 * (NC + 1);

  hipMemsetAsync(tot, 0, 3 * NC * sizeof(int), stream);
  const int total8 = N * KDIM / 8;
  prep_kernel<<<PREP_GRID, 256, 0, stream>>>(A, h, hb, Wf, P8, tot, out, total8);
  scan_off_kernel<<<1, 128, 0, stream>>>(tot, off, cursor);
  partition_coarse_kernel<<<dim3(NPB, 3), 256, 0, stream>>>(A, cursor, P2c, Emax);
  sort_fine_kernel<<<dim3(NC, 3), 512, 0, stream>>>(P2c, off, S, row_start, N, Emax);
  gemm_mfma_kernel<<<dim3((N + 127) / 128, 3), 512, 0, stream>>>(A, hb, Wf, P8, x, N);
  spmm_all_kernel<<<dim3(NBUCK, 3), 512, 0, stream>>>(A, S, row_start, x, out, N, Emax);
}

// Round 5
// 263.857 us; speedup vs baseline: 3.6238x; 1.8220x over previous
//
// ============================================================================
// Round 18: spmm reverted to R14-exact combine (serial-g, REGISTER acc, ONE
// coalesced write -- R15/R16/R17 proved LDS-atomic agg, random scatter, and
// device-atomic out all amplify catastrophically). Structural change this
// round: DELETE sort_fine. Partition now bins directly at BUCKET=64
// granularity (bin=dst>>6, payload src|(dst&63)<<16, 782 bins); spmm
// counting-sorts its own bucket in LDS (64-bin hist + wave shfl_up scan +
// scatter to u16) then runs the R14 accumulation. row_start/S deleted;
// deg derived locally.
//
// Measured R17: 480.8us; spmm 283, WRITE 300MB (atomicAdd out RMWs at
// memory-side coherence point, ~24x amplification). R14 ledger: spmm 69.3,
// middle ~199 (est: prep 30, scan 3, partition 50, sort 45, gemm 40).
//
// Predicted: spmm ~78-85 (FETCH ~153MB u32 edges, WRITE 12.5MB, conflicts
// +sort atomics ~50-100K), partition ~R14+-8, sort gone (-45, -1 boundary).
// Total -> ~235-250. absmax ~0.001953125 (intra-node fp32 order only).
// Pre-commit: total >= 265 => sort was cheap; next round fuses gemm into
// partition and attacks prep/partition.
// ============================================================================
#include <hip/hip_runtime.h>

#define KDIM 128
#define NCOLS 64
// u8-packed src-degree histogram: one range, 50000 bins / 4 per word
#define NHCH 64
#define HW 12500
// fine buckets (partition + spmm granularity)
#define BUCKET 64
#define NB7 782
#define FCAP 2816
// partition blocks per graph
#define NPB 85
// prep task ranges
#define PREP_HIST (3 * NHCH)   // 192 hist blocks
#define PREP_CNT  (3 * NPB)    // 255 bucket-count blocks
#define PREP_WF   12           // wfrag blocks
#define PREP_CONV 565          // h->bf16 blocks (grid-stride)
#define PREP_GRID (PREP_HIST + PREP_CNT + PREP_WF + PREP_CONV)  // 1024

typedef __attribute__((ext_vector_type(8))) short bf16x8;
typedef __attribute__((ext_vector_type(4))) float f32x4;

struct GArgs {
  const int*   src[3];
  const int*   dst[3];
  const float* W[3];
  const float* b[3];
  int          E[3];
};

__device__ __forceinline__ unsigned short f2bf(float f) {
  unsigned u = __float_as_uint(f);
  u += 0x7FFFu + ((u >> 16) & 1u);   // RNE
  return (unsigned short)(u >> 16);
}
__device__ __forceinline__ float bflo(unsigned u) { return __uint_as_float(u << 16); }
__device__ __forceinline__ float bfhi(unsigned u) { return __uint_as_float(u & 0xFFFF0000u); }

// ---------------- fused front-end: hist | count | wfrag | convert -----------
__global__ __launch_bounds__(256) void prep_kernel(
    GArgs A, const float* __restrict__ h, unsigned short* __restrict__ hb,
    unsigned short* __restrict__ Wf, unsigned* __restrict__ P8,
    int* __restrict__ tot, int total8) {
  __shared__ unsigned sbuf[HW];   // 50 KB; hist uses all, count uses prefix
  const int b = blockIdx.x;
  const int t = threadIdx.x;

  if (b < PREP_HIST) {
    // -------- u8-packed src histogram, single pass over all 50000 bins -----
    const int g = b >> 6;
    const int chunk = b & 63;
    const int E = A.E[g];
    const int per_chunk = (((E + NHCH - 1) / NHCH) + 3) & ~3;
    const int* __restrict__ keys = A.src[g];
    for (int i = t; i < HW; i += 256) sbuf[i] = 0;
    __syncthreads();
    const int e0 = chunk * per_chunk;
    const int e1 = min(e0 + per_chunk, E);
    const int nn = max(e1 - e0, 0);
    const int nv = nn >> 2;
    const int4* k4p = (const int4*)&keys[e0];
    for (int v = t; v < nv; v += 256) {
      int4 k = k4p[v];
      atomicAdd(&sbuf[(unsigned)k.x >> 2], 1u << (((unsigned)k.x & 3u) * 8));
      atomicAdd(&sbuf[(unsigned)k.y >> 2], 1u << (((unsigned)k.y & 3u) * 8));
      atomicAdd(&sbuf[(unsigned)k.z >> 2], 1u << (((unsigned)k.z & 3u) * 8));
      atomicAdd(&sbuf[(unsigned)k.w >> 2], 1u << (((unsigned)k.w & 3u) * 8));
    }
    for (int e = e0 + (nv << 2) + t; e < e1; e += 256) {
      unsigned k = (unsigned)keys[e];
      atomicAdd(&sbuf[k >> 2], 1u << ((k & 3u) * 8));
    }
    __syncthreads();
    unsigned* __restrict__ dstp = P8 + (size_t)b * HW;   // b == g*64+chunk
    for (int i = t; i < HW; i += 256) dstp[i] = sbuf[i];

  } else if (b < PREP_HIST + PREP_CNT) {
    // -------- fine bucket (dst>>6) count -----------------------------------
    const int bb = b - PREP_HIST;
    const int g = bb / NPB;
    const int blk = bb % NPB;
    const int E = A.E[g];
    const int per_block = (((E + NPB - 1) / NPB) + 3) & ~3;
    const int* __restrict__ dst = A.dst[g];
    int* hcnt = (int*)sbuf;
    for (int i = t; i < NB7; i += 256) hcnt[i] = 0;
    __syncthreads();
    const int e0 = blk * per_block;
    const int e1 = min(e0 + per_block, E);
    const int nn = max(e1 - e0, 0);
    const int nv = nn >> 2;
    const int4* d4 = (const int4*)&dst[e0];
    for (int v = t; v < nv; v += 256) {
      int4 d = d4[v];
      atomicAdd(&hcnt[(unsigned)d.x >> 6], 1);
      atomicAdd(&hcnt[(unsigned)d.y >> 6], 1);
      atomicAdd(&hcnt[(unsigned)d.z >> 6], 1);
      atomicAdd(&hcnt[(unsigned)d.w >> 6], 1);
    }
    for (int e = e0 + (nv << 2) + t; e < e1; e += 256)
      atomicAdd(&hcnt[(unsigned)dst[e] >> 6], 1);
    __syncthreads();
    for (int i = t; i < NB7; i += 256)
      if (hcnt[i]) atomicAdd(&tot[g * NB7 + i], hcnt[i]);

  } else if (b < PREP_HIST + PREP_CNT + PREP_WF) {
    // -------- W -> MFMA B-fragment layout, PERMUTED columns ----------------
    // B-frag (c, lane n) holds logical W column (4n + c): MFMA C/D at lane n,
    // acc[c][r] is logical col 4n+c -> contiguous 8B epilogue store.
    int tid = (b - PREP_HIST - PREP_CNT) * 256 + t;   // < 3072 always
    int lane = tid & 63;
    int frag = (tid >> 6) & 15;
    int g = tid >> 10;
    int c = frag >> 2, kk = frag & 3;
    int n = lane & 15, quad = lane >> 4;
    const float* W = A.W[g];
    unsigned short v[8];
    #pragma unroll
    for (int j = 0; j < 8; ++j) {
      int k = 32 * kk + quad * 8 + j;
      v[j] = f2bf(W[k * 64 + 4 * n + c]);
    }
    uint4 u;
    u.x = (unsigned)v[0] | ((unsigned)v[1] << 16);
    u.y = (unsigned)v[2] | ((unsigned)v[3] << 16);
    u.z = (unsigned)v[4] | ((unsigned)v[5] << 16);
    u.w = (unsigned)v[6] | ((unsigned)v[7] << 16);
    ((uint4*)Wf)[tid] = u;

  } else {
    // -------- h fp32 -> bf16, grid-stride ----------------------------------
    const int cb = b - (PREP_HIST + PREP_CNT + PREP_WF);
    for (int i = cb * 256 + t; i < total8; i += PREP_CONV * 256) {
      const float4* hp = (const float4*)(h + (size_t)i * 8);
      float4 f0 = hp[0];
      float4 f1 = hp[1];
      uint4 u;
      u.x = (unsigned)f2bf(f0.x) | ((unsigned)f2bf(f0.y) << 16);
      u.y = (unsigned)f2bf(f0.z) | ((unsigned)f2bf(f0.w) << 16);
      u.z = (unsigned)f2bf(f1.x) | ((unsigned)f2bf(f1.y) << 16);
      u.w = (unsigned)f2bf(f1.z) | ((unsigned)f2bf(f1.w) << 16);
      ((uint4*)hb)[i] = u;
    }
  }
}

// ---------------- exclusive scan over 782 bins per graph --------------------
__global__ __launch_bounds__(512) void scan782_kernel(
    const int* __restrict__ tot, int* __restrict__ off, int* __restrict__ cursor) {
  __shared__ int sd[512];
  const int g = blockIdx.x;
  const int t = threadIdx.x;
  int base = 0;
  for (int c0 = 0; c0 < NB7; c0 += 512) {
    int idx = c0 + t;
    int v = (idx < NB7) ? tot[g * NB7 + idx] : 0;
    sd[t] = v;
    __syncthreads();
    for (int o = 1; o < 512; o <<= 1) {
      int add = (t >= o) ? sd[t - o] : 0;
      __syncthreads();
      sd[t] += add;
      __syncthreads();
    }
    int excl = base + sd[t] - v;
    if (idx < NB7) {
      off[g * (NB7 + 1) + idx] = excl;
      cursor[g * NB7 + idx] = excl;
    }
    base += sd[511];
    __syncthreads();
  }
  if (t == 0) off[g * (NB7 + 1) + NB7] = base;
}

// ---------------- fine partition: P2[cursor[dst>>6]++] = src|(dst&63)<<16 ---
__global__ __launch_bounds__(256) void partition_fine_kernel(
    GArgs A, int* __restrict__ cursor, unsigned* __restrict__ P2, int Emax) {
  __shared__ int lcnt[NB7];
  __shared__ int lcur[NB7];
  const int g = blockIdx.y;
  const int E = A.E[g];
  const int per_block = (((E + NPB - 1) / NPB) + 3) & ~3;
  const int* __restrict__ src = A.src[g];
  const int* __restrict__ dst = A.dst[g];
  unsigned* __restrict__ P2g = P2 + (size_t)g * Emax;
  const int t = threadIdx.x;
  for (int i = t; i < NB7; i += 256) lcnt[i] = 0;
  __syncthreads();
  const int e0 = blockIdx.x * per_block;
  const int e1 = min(e0 + per_block, E);
  const int n = max(e1 - e0, 0);
  const int nv = n >> 2;
  const int4* d4 = (const int4*)&dst[e0];
  const int4* s4 = (const int4*)&src[e0];
  for (int v = t; v < nv; v += 256) {
    int4 d = d4[v];
    atomicAdd(&lcnt[(unsigned)d.x >> 6], 1);
    atomicAdd(&lcnt[(unsigned)d.y >> 6], 1);
    atomicAdd(&lcnt[(unsigned)d.z >> 6], 1);
    atomicAdd(&lcnt[(unsigned)d.w >> 6], 1);
  }
  for (int e = e0 + (nv << 2) + t; e < e1; e += 256)
    atomicAdd(&lcnt[(unsigned)dst[e] >> 6], 1);
  __syncthreads();
  for (int i = t; i < NB7; i += 256) {
    int c = lcnt[i];
    lcur[i] = c ? atomicAdd(&cursor[g * NB7 + i], c) : 0;
  }
  __syncthreads();
  for (int v = t; v < nv; v += 256) {
    int4 d = d4[v];
    int4 s = s4[v];
    unsigned bk; int pos;
    bk = (unsigned)d.x >> 6; pos = atomicAdd(&lcur[bk], 1);
    P2g[pos] = (unsigned)s.x | (((unsigned)d.x & 63u) << 16);
    bk = (unsigned)d.y >> 6; pos = atomicAdd(&lcur[bk], 1);
    P2g[pos] = (unsigned)s.y | (((unsigned)d.y & 63u) << 16);
    bk = (unsigned)d.z >> 6; pos = atomicAdd(&lcur[bk], 1);
    P2g[pos] = (unsigned)s.z | (((unsigned)d.z & 63u) << 16);
    bk = (unsigned)d.w >> 6; pos = atomicAdd(&lcur[bk], 1);
    P2g[pos] = (unsigned)s.w | (((unsigned)d.w & 63u) << 16);
  }
  for (int e = e0 + (nv << 2) + t; e < e1; e += 256) {
    unsigned d = (unsigned)dst[e];
    unsigned bk = d >> 6;
    int pos = atomicAdd(&lcur[bk], 1);
    P2g[pos] = (unsigned)src[e] | ((d & 63u) << 16);
  }
}

// ---------------- MFMA GEMM: x(bf16) = (hb @ W) * rsqrt(deg_out) ------------
__global__ __launch_bounds__(512) void gemm_mfma_kernel(
    GArgs A, const unsigned short* __restrict__ hb,
    const unsigned short* __restrict__ Wf, const unsigned* __restrict__ P8,
    unsigned short* __restrict__ x, int N) {
  __shared__ unsigned ldegw[64];   // [word 0..31][half 0..1] u16-packed degrees
  const int g = blockIdx.y;
  unsigned short* __restrict__ xg = x + (size_t)g * N * NCOLS;
  const int t = threadIdx.x;
  const int row0 = blockIdx.x * 128;

  if (t < 64) ldegw[t] = 0;
  __syncthreads();
  if (t < 256) {
    // 32 words x 8 chunk-groups; SWAR-sum 8 chunks then 2 LDS atomics
    const unsigned* __restrict__ Pg = P8 + (size_t)g * NHCH * HW;
    const int widx = t >> 3;
    const int cg = t & 7;
    const int wcol = min((row0 >> 2) + widx, HW - 1);
    unsigned lo = 0, hi = 0;
    #pragma unroll
    for (int cc = 0; cc < 8; ++cc) {
      unsigned wv = Pg[(size_t)(cg * 8 + cc) * HW + wcol];
      lo += wv & 0x00FF00FFu;
      hi += (wv >> 8) & 0x00FF00FFu;
    }
    atomicAdd(&ldegw[2 * widx], lo);
    atomicAdd(&ldegw[2 * widx + 1], hi);
  }

  const int lane = t & 63;
  const int w = t >> 6;              // wave id: rows row0+16w .. +15
  const int quad = lane >> 4;
  const int n = lane & 15;

  // A fragments: lane holds row (row0+16w+n), k = quad*8+j (+32 per frag)
  int arow = min(row0 + w * 16 + n, N - 1);
  const unsigned short* hrow = hb + (size_t)arow * KDIM + quad * 8;
  bf16x8 a0 = *(const bf16x8*)(hrow);
  bf16x8 a1 = *(const bf16x8*)(hrow + 32);
  bf16x8 a2 = *(const bf16x8*)(hrow + 64);
  bf16x8 a3 = *(const bf16x8*)(hrow + 96);

  const uint4* wfp = (const uint4*)Wf + (size_t)g * 1024 + lane;

  f32x4 acc[4];
  #pragma unroll
  for (int c = 0; c < 4; ++c) acc[c] = (f32x4)(0.f);

  __syncthreads();   // ldegw ready

  #pragma unroll
  for (int c = 0; c < 4; ++c) {
    union { uint4 u; bf16x8 v; } b0, b1, b2, b3;
    b0.u = wfp[(size_t)(c * 4 + 0) * 64];
    b1.u = wfp[(size_t)(c * 4 + 1) * 64];
    b2.u = wfp[(size_t)(c * 4 + 2) * 64];
    b3.u = wfp[(size_t)(c * 4 + 3) * 64];
    acc[c] = __builtin_amdgcn_mfma_f32_16x16x32_bf16(a0, b0.v, acc[c], 0, 0, 0);
    acc[c] = __builtin_amdgcn_mfma_f32_16x16x32_bf16(a1, b1.v, acc[c], 0, 0, 0);
    acc[c] = __builtin_amdgcn_mfma_f32_16x16x32_bf16(a2, b2.v, acc[c], 0, 0, 0);
    acc[c] = __builtin_amdgcn_mfma_f32_16x16x32_bf16(a3, b3.v, acc[c], 0, 0, 0);
  }

  // epilogue: C/D row = quad*4 + r, lane n owns logical cols 4n..4n+3
  const int rbase = row0 + w * 16 + quad * 4;
  #pragma unroll
  for (int r = 0; r < 4; ++r) {
    int row = rbase + r;
    if (row < N) {
      int lr = row - row0;
      float dg = (float)((ldegw[2 * (lr >> 2) + (lr & 1)] >> (((lr >> 1) & 1) * 16)) & 0xFFFFu);
      float s = rsqrtf(fmaxf(dg, 1.0f));
      uint2 o;
      o.x = (unsigned)f2bf(acc[0][r] * s) | ((unsigned)f2bf(acc[1][r] * s) << 16);
      o.y = (unsigned)f2bf(acc[2][r] * s) | ((unsigned)f2bf(acc[3][r] * s) << 16);
      *(uint2*)(xg + (size_t)row * NCOLS + 4 * n) = o;
    }
  }
}

// ---------------- SpMM: in-LDS counting sort + R14 register accumulation ----
__global__ __launch_bounds__(512) void spmm_all_kernel(
    GArgs A, const unsigned* __restrict__ P2, const int* __restrict__ off,
    const unsigned short* __restrict__ x, float* __restrict__ out,
    int N, int Emax) {
  __shared__ unsigned eb[FCAP];            // staged edges src|ldst<<16
  __shared__ unsigned short srcs[FCAP];    // node-sorted src ids
  __shared__ int cnt[BUCKET];
  __shared__ int cur[BUCKET];
  __shared__ int rsx[BUCKET + 1];

  const int t = threadIdx.x;
  const int bk = blockIdx.x;
  const int dbase = bk * BUCKET;
  const int nd = min(BUCKET, N - dbase);
  const int grp = t >> 3;
  const int qe = (t & 7) * 8;

  float tot[8];
  #pragma unroll
  for (int j = 0; j < 8; ++j) tot[j] = 0.f;

  for (int g = 0; g < 3; ++g) {
    const unsigned* __restrict__ P2g = P2 + (size_t)g * Emax;
    const unsigned short* __restrict__ xg = x + (size_t)g * N * NCOLS;

    __syncthreads();                       // previous-g reads complete
    if (t < BUCKET) cnt[t] = 0;
    __syncthreads();

    const int e0 = off[g * (NB7 + 1) + bk];
    const int ne = min(off[g * (NB7 + 1) + bk + 1] - e0, FCAP);
    for (int i = t; i < ne; i += 512) {
      unsigned e = P2g[e0 + i];
      eb[i] = e;
      atomicAdd(&cnt[e >> 16], 1);
    }
    __syncthreads();

    // wave-level exclusive scan of cnt[0..63] (lanes of wave 0, no syncs)
    if (t < BUCKET) {
      int v = cnt[t];
      int incl = v;
      #pragma unroll
      for (int o = 1; o < 64; o <<= 1) {
        int u = __shfl_up(incl, o, 64);
        if (t >= o) incl += u;
      }
      rsx[t + 1] = incl;
      cur[t] = incl - v;
      if (t == 0) rsx[0] = 0;
    }
    __syncthreads();

    for (int i = t; i < ne; i += 512) {
      unsigned e = eb[i];
      int pos = atomicAdd(&cur[e >> 16], 1);
      srcs[pos] = (unsigned short)(e & 0xFFFFu);
    }
    __syncthreads();

    if (grp < nd) {
      int i = rsx[grp];
      const int iend = rsx[grp + 1];
      const int deg = iend - i;
      float acc[8];
      #pragma unroll
      for (int j = 0; j < 8; ++j) acc[j] = 0.f;
      for (; i + 3 < iend; i += 4) {
        int sa = srcs[i + 0];
        int sb = srcs[i + 1];
        int sc = srcs[i + 2];
        int sdd = srcs[i + 3];
        uint4 ua = *(const uint4*)&xg[(size_t)sa * NCOLS + qe];
        uint4 ub = *(const uint4*)&xg[(size_t)sb * NCOLS + qe];
        uint4 uc = *(const uint4*)&xg[(size_t)sc * NCOLS + qe];
        uint4 ud = *(const uint4*)&xg[(size_t)sdd * NCOLS + qe];
        acc[0] += bflo(ua.x) + bflo(ub.x) + bflo(uc.x) + bflo(ud.x);
        acc[1] += bfhi(ua.x) + bfhi(ub.x) + bfhi(uc.x) + bfhi(ud.x);
        acc[2] += bflo(ua.y) + bflo(ub.y) + bflo(uc.y) + bflo(ud.y);
        acc[3] += bfhi(ua.y) + bfhi(ub.y) + bfhi(uc.y) + bfhi(ud.y);
        acc[4] += bflo(ua.z) + bflo(ub.z) + bflo(uc.z) + bflo(ud.z);
        acc[5] += bfhi(ua.z) + bfhi(ub.z) + bfhi(uc.z) + bfhi(ud.z);
        acc[6] += bflo(ua.w) + bflo(ub.w) + bflo(uc.w) + bflo(ud.w);
        acc[7] += bfhi(ua.w) + bfhi(ub.w) + bfhi(uc.w) + bfhi(ud.w);
      }
      for (; i < iend; ++i) {
        int s = srcs[i];
        uint4 u = *(const uint4*)&xg[(size_t)s * NCOLS + qe];
        acc[0] += bflo(u.x); acc[1] += bfhi(u.x);
        acc[2] += bflo(u.y); acc[3] += bfhi(u.y);
        acc[4] += bflo(u.z); acc[5] += bfhi(u.z);
        acc[6] += bflo(u.w); acc[7] += bfhi(u.w);
      }
      float sc2 = rsqrtf(fmaxf((float)deg, 1.0f));
      const float* bg = A.b[g] + qe;
      #pragma unroll
      for (int j = 0; j < 8; ++j)
        tot[j] += fmaxf(fmaf(acc[j], sc2, bg[j]), 0.f) * (1.0f / 3.0f);
    }
  }

  if (grp < nd) {
    float* op = &out[(size_t)(dbase + grp) * NCOLS + qe];
    *(float4*)&op[0] = make_float4(tot[0], tot[1], tot[2], tot[3]);
    *(float4*)&op[4] = make_float4(tot[4], tot[5], tot[6], tot[7]);
  }
}

extern "C" void kernel_launch(void* const* d_in, const int* in_sizes, int n_in,
                              void* d_out, int out_size, void* d_ws, size_t ws_size,
                              hipStream_t stream) {
  const float* h = (const float*)d_in[0];
  const int N = in_sizes[0] / KDIM;   // 50000
  float* out = (float*)d_out;

  GArgs A;
  int Emax = 0;
  for (int g = 0; g < 3; ++g) {
    A.src[g] = (const int*)  d_in[1 + g * 4];
    A.dst[g] = (const int*)  d_in[2 + g * 4];
    A.W[g]   = (const float*)d_in[3 + g * 4];
    A.b[g]   = (const float*)d_in[4 + g * 4];
    A.E[g]   = in_sizes[1 + g * 4];
    if (A.E[g] > Emax) Emax = A.E[g];
  }

  // ws: x 19.2 | hb 12.8 | P2 19.2 | P8 9.6 | Wf 48K | off/tot/cursor ~28 KB
  char* w = (char*)d_ws;
  unsigned short* x = (unsigned short*)w;
  char* w2 = w + (size_t)3 * N * NCOLS * sizeof(unsigned short);
  unsigned short* hb = (unsigned short*)w2;
  char* w3 = w2 + (size_t)N * KDIM * sizeof(unsigned short);
  unsigned* P2 = (unsigned*)w3;
  char* w4 = w3 + (size_t)3 * Emax * sizeof(unsigned);
  unsigned* P8 = (unsigned*)w4;
  char* w5 = w4 + (size_t)3 * NHCH * HW * sizeof(unsigned);
  unsigned short* Wf = (unsigned short*)w5;            // 3*16*64*8 u16 = 48 KB
  char* w6 = w5 + (size_t)3 * 16 * 64 * 8 * sizeof(unsigned short);
  int* tot    = (int*)w6;                              // [3][782]
  int* cursor = tot + 3 * NB7;                         // [3][782]
  int* off    = cursor + 3 * NB7;                      // [3][783]

  hipMemsetAsync(tot, 0, 3 * NB7 * sizeof(int), stream);
  const int total8 = N * KDIM / 8;
  prep_kernel<<<PREP_GRID, 256, 0, stream>>>(A, h, hb, Wf, P8, tot, total8);
  scan782_kernel<<<3, 512, 0, stream>>>(tot, off, cursor);
  partition_fine_kernel<<<dim3(NPB, 3), 256, 0, stream>>>(A, cursor, P2, Emax);
  gemm_mfma_kernel<<<dim3((N + 127) / 128, 3), 512, 0, stream>>>(A, hb, Wf, P8, x, N);
  spmm_all_kernel<<<NB7, 512, 0, stream>>>(A, P2, off, x, out, N, Emax);
}

// Round 6
// 251.811 us; speedup vs baseline: 3.7971x; 1.0478x over previous
//
// ============================================================================
// Round 19: (1) pg_kernel = partition_fine + gemm fused, block-specialized
// (255 partition blocks first -- long pole, memory-bound scatter; 1173 gemm
// blocks fill -- MFMA-bound, complementary pipes; R15 proved the pg structure
// co-schedules safely). (2) scan782 DELETED: each partition block redundantly
// computes exclscan(tot[g]) in LDS (~1-2us, amortized); blk==0 writes off for
// spmm; cursor zero-based (memset with tot). No numeric change anywhere.
// Pipeline: memset, prep, pg, spmm = 4 dispatches (was 5).
//
// Measured R18: 263.9us (best). spmm 75.1 (in-LDS sort +5.8 vs R14, conflicts
// 1.12M, FETCH 146MB, WRITE 12.5MB); middle ~189 (prep ~30, scan ~3,
// partition ~50-60, gemm ~40, 4 boundaries). sort_fine deletion netted ~10.
//
// Predicted: pg ~55-70 (FETCH ~95MB, WRITE ~38MB, MfmaUtil 5-10%) replacing
// ~90-100 of serial scan+partition+gemm+2 boundaries; spmm unchanged ~75;
// total -> ~230-242. absmax bit-identical 0.001953125. Pre-commit: pg >= 85
// -> cache interference, unfuse; spmm drift >3 -> L2 perturbation.
// ============================================================================
#include <hip/hip_runtime.h>

#define KDIM 128
#define NCOLS 64
// u8-packed src-degree histogram: one range, 50000 bins / 4 per word
#define NHCH 64
#define HW 12500
// fine buckets (partition + spmm granularity)
#define BUCKET 64
#define NB7 782
#define FCAP 2816
// partition blocks per graph
#define NPB 85
// prep task ranges
#define PREP_HIST (3 * NHCH)   // 192 hist blocks
#define PREP_CNT  (3 * NPB)    // 255 bucket-count blocks
#define PREP_WF   12           // wfrag blocks
#define PREP_CONV 565          // h->bf16 blocks (grid-stride)
#define PREP_GRID (PREP_HIST + PREP_CNT + PREP_WF + PREP_CONV)  // 1024
// pg (partition + gemm fused): partition FIRST (long pole)
#define PG_PART (3 * NPB)            // 255
#define PG_GEMM_PER 391              // (50000+127)/128
#define PG_GEMM (3 * PG_GEMM_PER)    // 1173
#define PG_GRID (PG_PART + PG_GEMM)  // 1428

typedef __attribute__((ext_vector_type(8))) short bf16x8;
typedef __attribute__((ext_vector_type(4))) float f32x4;

struct GArgs {
  const int*   src[3];
  const int*   dst[3];
  const float* W[3];
  const float* b[3];
  int          E[3];
};

__device__ __forceinline__ unsigned short f2bf(float f) {
  unsigned u = __float_as_uint(f);
  u += 0x7FFFu + ((u >> 16) & 1u);   // RNE
  return (unsigned short)(u >> 16);
}
__device__ __forceinline__ float bflo(unsigned u) { return __uint_as_float(u << 16); }
__device__ __forceinline__ float bfhi(unsigned u) { return __uint_as_float(u & 0xFFFF0000u); }

// ---------------- fused front-end: hist | count | wfrag | convert -----------
__global__ __launch_bounds__(256) void prep_kernel(
    GArgs A, const float* __restrict__ h, unsigned short* __restrict__ hb,
    unsigned short* __restrict__ Wf, unsigned* __restrict__ P8,
    int* __restrict__ tot, int total8) {
  __shared__ unsigned sbuf[HW];   // 50 KB; hist uses all, count uses prefix
  const int b = blockIdx.x;
  const int t = threadIdx.x;

  if (b < PREP_HIST) {
    // -------- u8-packed src histogram, single pass over all 50000 bins -----
    const int g = b >> 6;
    const int chunk = b & 63;
    const int E = A.E[g];
    const int per_chunk = (((E + NHCH - 1) / NHCH) + 3) & ~3;
    const int* __restrict__ keys = A.src[g];
    for (int i = t; i < HW; i += 256) sbuf[i] = 0;
    __syncthreads();
    const int e0 = chunk * per_chunk;
    const int e1 = min(e0 + per_chunk, E);
    const int nn = max(e1 - e0, 0);
    const int nv = nn >> 2;
    const int4* k4p = (const int4*)&keys[e0];
    for (int v = t; v < nv; v += 256) {
      int4 k = k4p[v];
      atomicAdd(&sbuf[(unsigned)k.x >> 2], 1u << (((unsigned)k.x & 3u) * 8));
      atomicAdd(&sbuf[(unsigned)k.y >> 2], 1u << (((unsigned)k.y & 3u) * 8));
      atomicAdd(&sbuf[(unsigned)k.z >> 2], 1u << (((unsigned)k.z & 3u) * 8));
      atomicAdd(&sbuf[(unsigned)k.w >> 2], 1u << (((unsigned)k.w & 3u) * 8));
    }
    for (int e = e0 + (nv << 2) + t; e < e1; e += 256) {
      unsigned k = (unsigned)keys[e];
      atomicAdd(&sbuf[k >> 2], 1u << ((k & 3u) * 8));
    }
    __syncthreads();
    unsigned* __restrict__ dstp = P8 + (size_t)b * HW;   // b == g*64+chunk
    for (int i = t; i < HW; i += 256) dstp[i] = sbuf[i];

  } else if (b < PREP_HIST + PREP_CNT) {
    // -------- fine bucket (dst>>6) count -----------------------------------
    const int bb = b - PREP_HIST;
    const int g = bb / NPB;
    const int blk = bb % NPB;
    const int E = A.E[g];
    const int per_block = (((E + NPB - 1) / NPB) + 3) & ~3;
    const int* __restrict__ dst = A.dst[g];
    int* hcnt = (int*)sbuf;
    for (int i = t; i < NB7; i += 256) hcnt[i] = 0;
    __syncthreads();
    const int e0 = blk * per_block;
    const int e1 = min(e0 + per_block, E);
    const int nn = max(e1 - e0, 0);
    const int nv = nn >> 2;
    const int4* d4 = (const int4*)&dst[e0];
    for (int v = t; v < nv; v += 256) {
      int4 d = d4[v];
      atomicAdd(&hcnt[(unsigned)d.x >> 6], 1);
      atomicAdd(&hcnt[(unsigned)d.y >> 6], 1);
      atomicAdd(&hcnt[(unsigned)d.z >> 6], 1);
      atomicAdd(&hcnt[(unsigned)d.w >> 6], 1);
    }
    for (int e = e0 + (nv << 2) + t; e < e1; e += 256)
      atomicAdd(&hcnt[(unsigned)dst[e] >> 6], 1);
    __syncthreads();
    for (int i = t; i < NB7; i += 256)
      if (hcnt[i]) atomicAdd(&tot[g * NB7 + i], hcnt[i]);

  } else if (b < PREP_HIST + PREP_CNT + PREP_WF) {
    // -------- W -> MFMA B-fragment layout, PERMUTED columns ----------------
    // B-frag (c, lane n) holds logical W column (4n + c): MFMA C/D at lane n,
    // acc[c][r] is logical col 4n+c -> contiguous 8B epilogue store.
    int tid = (b - PREP_HIST - PREP_CNT) * 256 + t;   // < 3072 always
    int lane = tid & 63;
    int frag = (tid >> 6) & 15;
    int g = tid >> 10;
    int c = frag >> 2, kk = frag & 3;
    int n = lane & 15, quad = lane >> 4;
    const float* W = A.W[g];
    unsigned short v[8];
    #pragma unroll
    for (int j = 0; j < 8; ++j) {
      int k = 32 * kk + quad * 8 + j;
      v[j] = f2bf(W[k * 64 + 4 * n + c]);
    }
    uint4 u;
    u.x = (unsigned)v[0] | ((unsigned)v[1] << 16);
    u.y = (unsigned)v[2] | ((unsigned)v[3] << 16);
    u.z = (unsigned)v[4] | ((unsigned)v[5] << 16);
    u.w = (unsigned)v[6] | ((unsigned)v[7] << 16);
    ((uint4*)Wf)[tid] = u;

  } else {
    // -------- h fp32 -> bf16, grid-stride ----------------------------------
    const int cb = b - (PREP_HIST + PREP_CNT + PREP_WF);
    for (int i = cb * 256 + t; i < total8; i += PREP_CONV * 256) {
      const float4* hp = (const float4*)(h + (size_t)i * 8);
      float4 f0 = hp[0];
      float4 f1 = hp[1];
      uint4 u;
      u.x = (unsigned)f2bf(f0.x) | ((unsigned)f2bf(f0.y) << 16);
      u.y = (unsigned)f2bf(f0.z) | ((unsigned)f2bf(f0.w) << 16);
      u.z = (unsigned)f2bf(f1.x) | ((unsigned)f2bf(f1.y) << 16);
      u.w = (unsigned)f2bf(f1.z) | ((unsigned)f2bf(f1.w) << 16);
      ((uint4*)hb)[i] = u;
    }
  }
}

// ---------------- fused partition + MFMA GEMM -------------------------------
__global__ __launch_bounds__(512) void pg_kernel(
    GArgs A, const unsigned short* __restrict__ hb,
    const unsigned short* __restrict__ Wf, const unsigned* __restrict__ P8,
    const int* __restrict__ tot, int* __restrict__ cursor,
    int* __restrict__ off, unsigned* __restrict__ P2,
    unsigned short* __restrict__ x, int N, int Emax) {
  __shared__ int lcnt[NB7];
  __shared__ int lcur[NB7];
  __shared__ int sd[512];
  const int b = blockIdx.x;
  const int t = threadIdx.x;

  if (b < PG_PART) {
    // ---------------- fine partition (512 thr, zero-based cursor) ----------
    const int g = b / NPB;
    const int blk = b % NPB;
    const int E = A.E[g];
    const int per_block = (((E + NPB - 1) / NPB) + 3) & ~3;
    const int* __restrict__ src = A.src[g];
    const int* __restrict__ dst = A.dst[g];
    unsigned* __restrict__ P2g = P2 + (size_t)g * Emax;

    for (int i = t; i < NB7; i += 512) lcnt[i] = 0;
    __syncthreads();
    const int e0 = blk * per_block;
    const int e1 = min(e0 + per_block, E);
    const int nn = max(e1 - e0, 0);
    const int nv = nn >> 2;
    const int4* d4 = (const int4*)&dst[e0];
    const int4* s4 = (const int4*)&src[e0];
    for (int v = t; v < nv; v += 512) {
      int4 d = d4[v];
      atomicAdd(&lcnt[(unsigned)d.x >> 6], 1);
      atomicAdd(&lcnt[(unsigned)d.y >> 6], 1);
      atomicAdd(&lcnt[(unsigned)d.z >> 6], 1);
      atomicAdd(&lcnt[(unsigned)d.w >> 6], 1);
    }
    for (int e = e0 + (nv << 2) + t; e < e1; e += 512)
      atomicAdd(&lcnt[(unsigned)dst[e] >> 6], 1);
    __syncthreads();

    // redundant exclusive scan of tot[g] over 782 bins (replaces scan782)
    int base = 0;
    for (int c0 = 0; c0 < NB7; c0 += 512) {
      int idx = c0 + t;
      int v = (idx < NB7) ? tot[g * NB7 + idx] : 0;
      sd[t] = v;
      __syncthreads();
      for (int o = 1; o < 512; o <<= 1) {
        int add = (t >= o) ? sd[t - o] : 0;
        __syncthreads();
        sd[t] += add;
        __syncthreads();
      }
      int excl = base + sd[t] - v;
      if (idx < NB7) {
        lcur[idx] = excl;
        if (blk == 0) off[g * (NB7 + 1) + idx] = excl;
      }
      base += sd[511];
      __syncthreads();
    }
    if (blk == 0 && t == 0) off[g * (NB7 + 1) + NB7] = base;

    // reserve this block's region per bin
    for (int i = t; i < NB7; i += 512) {
      int c = lcnt[i];
      if (c) lcur[i] += atomicAdd(&cursor[g * NB7 + i], c);
    }
    __syncthreads();

    for (int v = t; v < nv; v += 512) {
      int4 d = d4[v];
      int4 s = s4[v];
      unsigned bk; int pos;
      bk = (unsigned)d.x >> 6; pos = atomicAdd(&lcur[bk], 1);
      P2g[pos] = (unsigned)s.x | (((unsigned)d.x & 63u) << 16);
      bk = (unsigned)d.y >> 6; pos = atomicAdd(&lcur[bk], 1);
      P2g[pos] = (unsigned)s.y | (((unsigned)d.y & 63u) << 16);
      bk = (unsigned)d.z >> 6; pos = atomicAdd(&lcur[bk], 1);
      P2g[pos] = (unsigned)s.z | (((unsigned)d.z & 63u) << 16);
      bk = (unsigned)d.w >> 6; pos = atomicAdd(&lcur[bk], 1);
      P2g[pos] = (unsigned)s.w | (((unsigned)d.w & 63u) << 16);
    }
    for (int e = e0 + (nv << 2) + t; e < e1; e += 512) {
      unsigned d = (unsigned)dst[e];
      unsigned bk = d >> 6;
      int pos = atomicAdd(&lcur[bk], 1);
      P2g[pos] = (unsigned)src[e] | ((d & 63u) << 16);
    }

  } else {
    // ---------------- MFMA GEMM (R14/R18-verified) -------------------------
    unsigned* ldegw = (unsigned*)lcnt;   // 64 u16-packed degrees
    const int gb = b - PG_PART;
    const int g = gb / PG_GEMM_PER;
    const int blk = gb % PG_GEMM_PER;
    const int row0 = blk * 128;
    unsigned short* __restrict__ xg = x + (size_t)g * N * NCOLS;

    if (t < 64) ldegw[t] = 0;
    __syncthreads();
    if (t < 256) {
      const unsigned* __restrict__ Pg = P8 + (size_t)g * NHCH * HW;
      const int widx = t >> 3;
      const int cg = t & 7;
      const int wcol = min((row0 >> 2) + widx, HW - 1);
      unsigned lo = 0, hi = 0;
      #pragma unroll
      for (int cc = 0; cc < 8; ++cc) {
        unsigned wv = Pg[(size_t)(cg * 8 + cc) * HW + wcol];
        lo += wv & 0x00FF00FFu;
        hi += (wv >> 8) & 0x00FF00FFu;
      }
      atomicAdd(&ldegw[2 * widx], lo);
      atomicAdd(&ldegw[2 * widx + 1], hi);
    }

    const int lane = t & 63;
    const int w = t >> 6;              // wave id: rows row0+16w .. +15
    const int quad = lane >> 4;
    const int n = lane & 15;

    int arow = min(row0 + w * 16 + n, N - 1);
    const unsigned short* hrow = hb + (size_t)arow * KDIM + quad * 8;
    bf16x8 a0 = *(const bf16x8*)(hrow);
    bf16x8 a1 = *(const bf16x8*)(hrow + 32);
    bf16x8 a2 = *(const bf16x8*)(hrow + 64);
    bf16x8 a3 = *(const bf16x8*)(hrow + 96);

    const uint4* wfp = (const uint4*)Wf + (size_t)g * 1024 + lane;

    f32x4 acc[4];
    #pragma unroll
    for (int c = 0; c < 4; ++c) acc[c] = (f32x4)(0.f);

    __syncthreads();   // ldegw ready

    #pragma unroll
    for (int c = 0; c < 4; ++c) {
      union { uint4 u; bf16x8 v; } b0, b1, b2, b3;
      b0.u = wfp[(size_t)(c * 4 + 0) * 64];
      b1.u = wfp[(size_t)(c * 4 + 1) * 64];
      b2.u = wfp[(size_t)(c * 4 + 2) * 64];
      b3.u = wfp[(size_t)(c * 4 + 3) * 64];
      acc[c] = __builtin_amdgcn_mfma_f32_16x16x32_bf16(a0, b0.v, acc[c], 0, 0, 0);
      acc[c] = __builtin_amdgcn_mfma_f32_16x16x32_bf16(a1, b1.v, acc[c], 0, 0, 0);
      acc[c] = __builtin_amdgcn_mfma_f32_16x16x32_bf16(a2, b2.v, acc[c], 0, 0, 0);
      acc[c] = __builtin_amdgcn_mfma_f32_16x16x32_bf16(a3, b3.v, acc[c], 0, 0, 0);
    }

    const int rbase = row0 + w * 16 + quad * 4;
    #pragma unroll
    for (int r = 0; r < 4; ++r) {
      int row = rbase + r;
      if (row < N) {
        int lr = row - row0;
        float dg = (float)((ldegw[2 * (lr >> 2) + (lr & 1)] >> (((lr >> 1) & 1) * 16)) & 0xFFFFu);
        float s = rsqrtf(fmaxf(dg, 1.0f));
        uint2 o;
        o.x = (unsigned)f2bf(acc[0][r] * s) | ((unsigned)f2bf(acc[1][r] * s) << 16);
        o.y = (unsigned)f2bf(acc[2][r] * s) | ((unsigned)f2bf(acc[3][r] * s) << 16);
        *(uint2*)(xg + (size_t)row * NCOLS + 4 * n) = o;
      }
    }
  }
}

// ---------------- SpMM: in-LDS counting sort + register accumulation --------
__global__ __launch_bounds__(512) void spmm_all_kernel(
    GArgs A, const unsigned* __restrict__ P2, const int* __restrict__ off,
    const unsigned short* __restrict__ x, float* __restrict__ out,
    int N, int Emax) {
  __shared__ unsigned eb[FCAP];            // staged edges src|ldst<<16
  __shared__ unsigned short srcs[FCAP];    // node-sorted src ids
  __shared__ int cnt[BUCKET];
  __shared__ int cur[BUCKET];
  __shared__ int rsx[BUCKET + 1];

  const int t = threadIdx.x;
  const int bk = blockIdx.x;
  const int dbase = bk * BUCKET;
  const int nd = min(BUCKET, N - dbase);
  const int grp = t >> 3;
  const int qe = (t & 7) * 8;

  float tot[8];
  #pragma unroll
  for (int j = 0; j < 8; ++j) tot[j] = 0.f;

  for (int g = 0; g < 3; ++g) {
    const unsigned* __restrict__ P2g = P2 + (size_t)g * Emax;
    const unsigned short* __restrict__ xg = x + (size_t)g * N * NCOLS;

    __syncthreads();                       // previous-g reads complete
    if (t < BUCKET) cnt[t] = 0;
    __syncthreads();

    const int e0 = off[g * (NB7 + 1) + bk];
    const int ne = min(off[g * (NB7 + 1) + bk + 1] - e0, FCAP);
    for (int i = t; i < ne; i += 512) {
      unsigned e = P2g[e0 + i];
      eb[i] = e;
      atomicAdd(&cnt[e >> 16], 1);
    }
    __syncthreads();

    // wave-level exclusive scan of cnt[0..63] (lanes of wave 0, no syncs)
    if (t < BUCKET) {
      int v = cnt[t];
      int incl = v;
      #pragma unroll
      for (int o = 1; o < 64; o <<= 1) {
        int u = __shfl_up(incl, o, 64);
        if (t >= o) incl += u;
      }
      rsx[t + 1] = incl;
      cur[t] = incl - v;
      if (t == 0) rsx[0] = 0;
    }
    __syncthreads();

    for (int i = t; i < ne; i += 512) {
      unsigned e = eb[i];
      int pos = atomicAdd(&cur[e >> 16], 1);
      srcs[pos] = (unsigned short)(e & 0xFFFFu);
    }
    __syncthreads();

    if (grp < nd) {
      int i = rsx[grp];
      const int iend = rsx[grp + 1];
      const int deg = iend - i;
      float acc[8];
      #pragma unroll
      for (int j = 0; j < 8; ++j) acc[j] = 0.f;
      for (; i + 3 < iend; i += 4) {
        int sa = srcs[i + 0];
        int sb = srcs[i + 1];
        int sc = srcs[i + 2];
        int sdd = srcs[i + 3];
        uint4 ua = *(const uint4*)&xg[(size_t)sa * NCOLS + qe];
        uint4 ub = *(const uint4*)&xg[(size_t)sb * NCOLS + qe];
        uint4 uc = *(const uint4*)&xg[(size_t)sc * NCOLS + qe];
        uint4 ud = *(const uint4*)&xg[(size_t)sdd * NCOLS + qe];
        acc[0] += bflo(ua.x) + bflo(ub.x) + bflo(uc.x) + bflo(ud.x);
        acc[1] += bfhi(ua.x) + bfhi(ub.x) + bfhi(uc.x) + bfhi(ud.x);
        acc[2] += bflo(ua.y) + bflo(ub.y) + bflo(uc.y) + bflo(ud.y);
        acc[3] += bfhi(ua.y) + bfhi(ub.y) + bfhi(uc.y) + bfhi(ud.y);
        acc[4] += bflo(ua.z) + bflo(ub.z) + bflo(uc.z) + bflo(ud.z);
        acc[5] += bfhi(ua.z) + bfhi(ub.z) + bfhi(uc.z) + bfhi(ud.z);
        acc[6] += bflo(ua.w) + bflo(ub.w) + bflo(uc.w) + bflo(ud.w);
        acc[7] += bfhi(ua.w) + bfhi(ub.w) + bfhi(uc.w) + bfhi(ud.w);
      }
      for (; i < iend; ++i) {
        int s = srcs[i];
        uint4 u = *(const uint4*)&xg[(size_t)s * NCOLS + qe];
        acc[0] += bflo(u.x); acc[1] += bfhi(u.x);
        acc[2] += bflo(u.y); acc[3] += bfhi(u.y);
        acc[4] += bflo(u.z); acc[5] += bfhi(u.z);
        acc[6] += bflo(u.w); acc[7] += bfhi(u.w);
      }
      float sc2 = rsqrtf(fmaxf((float)deg, 1.0f));
      const float* bg = A.b[g] + qe;
      #pragma unroll
      for (int j = 0; j < 8; ++j)
        tot[j] += fmaxf(fmaf(acc[j], sc2, bg[j]), 0.f) * (1.0f / 3.0f);
    }
  }

  if (grp < nd) {
    float* op = &out[(size_t)(dbase + grp) * NCOLS + qe];
    *(float4*)&op[0] = make_float4(tot[0], tot[1], tot[2], tot[3]);
    *(float4*)&op[4] = make_float4(tot[4], tot[5], tot[6], tot[7]);
  }
}

extern "C" void kernel_launch(void* const* d_in, const int* in_sizes, int n_in,
                              void* d_out, int out_size, void* d_ws, size_t ws_size,
                              hipStream_t stream) {
  const float* h = (const float*)d_in[0];
  const int N = in_sizes[0] / KDIM;   // 50000
  float* out = (float*)d_out;

  GArgs A;
  int Emax = 0;
  for (int g = 0; g < 3; ++g) {
    A.src[g] = (const int*)  d_in[1 + g * 4];
    A.dst[g] = (const int*)  d_in[2 + g * 4];
    A.W[g]   = (const float*)d_in[3 + g * 4];
    A.b[g]   = (const float*)d_in[4 + g * 4];
    A.E[g]   = in_sizes[1 + g * 4];
    if (A.E[g] > Emax) Emax = A.E[g];
  }

  // ws: x 19.2 | hb 12.8 | P2 19.2 | P8 9.6 | Wf 48K | tot/cursor/off ~28 KB
  char* w = (char*)d_ws;
  unsigned short* x = (unsigned short*)w;
  char* w2 = w + (size_t)3 * N * NCOLS * sizeof(unsigned short);
  unsigned short* hb = (unsigned short*)w2;
  char* w3 = w2 + (size_t)N * KDIM * sizeof(unsigned short);
  unsigned* P2 = (unsigned*)w3;
  char* w4 = w3 + (size_t)3 * Emax * sizeof(unsigned);
  unsigned* P8 = (unsigned*)w4;
  char* w5 = w4 + (size_t)3 * NHCH * HW * sizeof(unsigned);
  unsigned short* Wf = (unsigned short*)w5;            // 3*16*64*8 u16 = 48 KB
  char* w6 = w5 + (size_t)3 * 16 * 64 * 8 * sizeof(unsigned short);
  int* tot    = (int*)w6;                              // [3][782]
  int* cursor = tot + 3 * NB7;                         // [3][782]
  int* off    = cursor + 3 * NB7;                      // [3][783]

  hipMemsetAsync(tot, 0, 2 * 3 * NB7 * sizeof(int), stream);
  const int total8 = N * KDIM / 8;
  prep_kernel<<<PREP_GRID, 256, 0, stream>>>(A, h, hb, Wf, P8, tot, total8);
  pg_kernel<<<PG_GRID, 512, 0, stream>>>(A, hb, Wf, P8, tot, cursor, off, P2, x, N, Emax);
  spmm_all_kernel<<<NB7, 512, 0, stream>>>(A, P2, off, x, out, N, Emax);
}